// Round 6
// baseline (588.319 us; speedup 1.0000x reference)
//
#include <hip/hip_runtime.h>
#include <math.h>

// ---- problem constants ----
#define NPAD 132                 // padded row stride for 130x130 matrices
#define TSTEPS 131071            // number of RK4 steps (T-1)
#define LCH 128                  // chunk length
#define NCH 1024                 // number of chunks
#define PERIOD 2880              // steps per day: forcing q(t) exactly periodic
#define OMEGA 7.2722052166430399e-05f   // 2*pi/86400

// ---- workspace layout (float offsets) ----
#define OFF_A    0
#define OFF_A2   17160
#define OFF_A3   34320
#define OFF_M    51480
#define OFF_C1   68640
#define OFF_C2   85800
#define OFF_P1   102960
#define OFF_P2   120120          // A^4 until squarings reuse it
#define OFF_M2   137280
#define OFF_M4   154440
#define OFF_M64  171600
#define OFF_M128 188760
#define OFF_M2K  205920
#define OFF_C1T  223080          // [128][128]
#define OFF_C2T  239464
#define OFF_C1B  255848
#define OFF_C2B  255978
#define OFF_C3B  256108
#define OFF_AMP  256238
#define OFF_CPH  256366
#define OFF_SPH  256494
#define OFF_SH   256622
#define OFF_W    256750          // [9][130] stride-4 forcing vectors
#define OFF_G    257920          // [NCH][130]
#define OFF_S64  391040          // [NCH][130] partial at 64 steps
#define OFF_XB   524160          // [NCH][130] chunk boundaries
#define OFF_XB2  657280          // [2*NCH][130] half-chunk boundaries
#define OFF_SA   923520          // [63][130] superchunk accums
#define OFF_GP   931710          // [PERIOD][130] periodic forcing P
#define OFF_GP2  1306110         // [PERIOD][130] P2
#define OFF_GP4  1680510         // [PERIOD][130] P4
#define OFF_TT   2054910         // float2[131080] (tg, tm)

// pin a loaded float4 into VGPRs: "+v" makes rematerialization (re-loading
// from memory inside the loop) illegal -- r5 showed the compiler otherwise
// drops mr[] to 84 VGPRs and re-reads M from L2 every step.
#define PIN4(v) asm volatile("" : "+v"((v).x), "+v"((v).y), "+v"((v).z), "+v"((v).w))

__device__ __forceinline__ float sigm(float x) { return 1.0f / (1.0f + expf(-x)); }

__device__ __forceinline__ float interp_tout(float t, const float* __restrict__ tv) {
    float u = t * (1.0f / 3600.0f);
    int idx = (int)u;
    if (idx > 1098) idx = 1098;
    float fr = u - (float)idx;
    float v0 = tv[idx];
    return v0 + fr * (tv[idx + 1] - v0);
}

// ---------------- build_A ----------------
__global__ __launch_bounds__(256) void build_A_kernel(
    const float* __restrict__ params, const float* __restrict__ heating,
    const float* __restrict__ Bm, const float* __restrict__ tout_v,
    float* __restrict__ ws, float* __restrict__ out) {
    const int tid = threadIdx.x;
    float* A = ws + OFF_A;

    for (int idx = tid; idx < 130 * 130; idx += 256) {
        int r = idx / 130, c = idx - r * 130;
        A[r * NPAD + c] = sigm(params[idx]) * 1e-5f;
    }
    for (int r = tid; r < 130; r += 256) { A[r * NPAD + 130] = 0.f; A[r * NPAD + 131] = 0.f; }
    __syncthreads();
    for (int r = tid; r < 130; r += 256) {
        float s = 0.0f;
        for (int k = 0; k < 130; ++k) s += A[r * NPAD + k];
        A[r * NPAD + r] = -s;
    }
    for (int i = tid; i < 128; i += 256) {
        float bd = Bm[(2 + i) * 129 + (1 + i)];
        ws[OFF_AMP + i] = sigm(heating[i * 3]) * 500.0f * bd;
        float ph = heating[i * 3 + 1];
        ws[OFF_CPH + i] = cosf(ph);
        ws[OFF_SPH + i] = sinf(ph);
        ws[OFF_SH + i]  = heating[i * 3 + 2];
    }
    float iv = tout_v[0] + 4.0f;
    for (int i = tid; i < 128; i += 256) out[i] = iv;
    for (int r = tid; r < 130; r += 256) ws[OFF_XB + r] = iv;
}

// ---------------- mm: dst = X*Y, one block per output row ----------
__global__ __launch_bounds__(192) void mm_kernel(float* __restrict__ ws,
                                                 int offD, int offX, int offY) {
    const float* X = ws + offX;
    const float* Y = ws + offY;
    float* dst = ws + offD;
    __shared__ float xrow[130];
    const int r = blockIdx.x;
    const int c = threadIdx.x;
    if (c < 130) xrow[c] = X[r * NPAD + c];
    __syncthreads();
    if (c < 130) {
        float acc = 0.0f;
#pragma unroll 10
        for (int k = 0; k < 130; ++k)
            acc = fmaf(xrow[k], Y[k * NPAD + c], acc);
        dst[r * NPAD + c] = acc;
    }
    if (c >= 130 && c < 132) dst[r * NPAD + c] = 0.0f;
}

// ---------------- mm34: A3 = A*A2 (blocks 0..129), A4 = A2*A2 (130..259) -----
__global__ __launch_bounds__(192) void mm34_kernel(float* __restrict__ ws) {
    const int b = blockIdx.x;
    const bool hi = (b >= 130);
    const int r = hi ? b - 130 : b;
    const float* X = ws + (hi ? OFF_A2 : OFF_A);
    const float* Y = ws + OFF_A2;
    float* dst = ws + (hi ? OFF_P2 : OFF_A3);
    __shared__ float xrow[130];
    const int c = threadIdx.x;
    if (c < 130) xrow[c] = X[r * NPAD + c];
    __syncthreads();
    if (c < 130) {
        float acc = 0.0f;
#pragma unroll 10
        for (int k = 0; k < 130; ++k)
            acc = fmaf(xrow[k], Y[k * NPAD + c], acc);
        dst[r * NPAD + c] = acc;
    }
    if (c >= 130 && c < 132) dst[r * NPAD + c] = 0.0f;
}

// ---------------- combine: M, C1, C2 (+ transposed room blocks) --------------
__global__ __launch_bounds__(256) void combine_kernel(float* __restrict__ ws) {
    int idx = blockIdx.x * 256 + threadIdx.x;
    if (idx >= 130 * 130) return;
    int r = idx / 130, c = idx - r * 130;
    int o = r * NPAD + c;
    const float* A  = ws + OFF_A;
    const float* A2 = ws + OFF_A2;
    const float* A3 = ws + OFF_A3;
    const float* A4 = ws + OFF_P2;
    float eye = (r == c) ? 1.0f : 0.0f;
    float a = A[o], a2 = A2[o], a3 = A3[o], a4 = A4[o];
    float c1v = 5.0f * eye + 150.0f * a + 2250.0f * a2 + 33750.0f * a3;
    float c2v = 20.0f * eye + 300.0f * a + 2250.0f * a2;
    ws[OFF_M  + o] = eye + 30.0f * a + 450.0f * a2 + 4500.0f * a3 + 33750.0f * a4;
    ws[OFF_C1 + o] = c1v;
    ws[OFF_C2 + o] = c2v;
    if (r >= 2 && c >= 2) {
        ws[OFF_C1T + (c - 2) * 128 + (r - 2)] = c1v;
        ws[OFF_C2T + (c - 2) * 128 + (r - 2)] = c2v;
    }
    if (c == 0) {
        ws[OFF_M + r * NPAD + 130] = 0.f; ws[OFF_M + r * NPAD + 131] = 0.f;
        ws[OFF_C1 + r * NPAD + 130] = 0.f; ws[OFF_C1 + r * NPAD + 131] = 0.f;
        ws[OFF_C2 + r * NPAD + 130] = 0.f; ws[OFF_C2 + r * NPAD + 131] = 0.f;
    }
}

// ---------------- vecs2: c1b/c2b/c3b + the 9 stride-4 W vectors --------------
// W0=M3c1b W1=M3c2b W2=M3c3b+M2c1b W3=M2c2b W4=M2c3b+Mc1b W5=Mc2b
// W6=Mc3b+c1b W7=c2b W8=c3b
__global__ __launch_bounds__(192) void vecs2_kernel(const float* __restrict__ Bm,
                                                    float* __restrict__ ws) {
    const int r = threadIdx.x;
    const float* C1 = ws + OFF_C1;
    const float* C2 = ws + OFF_C2;
    const float* Mm = ws + OFF_M;
    __shared__ __align__(16) float va[132], vb[132], vd[132];
    __shared__ __align__(16) float na[132], nb[132], nd[132];
    __shared__ float a1s[130], a2s[130], c1bs[130];

    if (r < 132) { va[r] = 0.f; vb[r] = 0.f; vd[r] = 0.f; na[r] = 0.f; nb[r] = 0.f; nd[r] = 0.f; }
    __syncthreads();
    if (r < 130) {
        float s1 = 0.0f, s2 = 0.0f;
        for (int k = 0; k < 130; ++k) {
            float b0 = Bm[k * 129];
            s1 = fmaf(C1[r * NPAD + k], b0, s1);
            s2 = fmaf(C2[r * NPAD + k], b0, s2);
        }
        float c3 = 5.0f * Bm[r * 129];
        ws[OFF_C1B + r] = s1; ws[OFF_C2B + r] = s2; ws[OFF_C3B + r] = c3;
        ws[OFF_W + 7 * 130 + r] = s2;   // W7
        ws[OFF_W + 8 * 130 + r] = c3;   // W8
        va[r] = s1; vb[r] = s2; vd[r] = c3; c1bs[r] = s1;
    }
    __syncthreads();

    for (int st = 1; st <= 3; ++st) {
        if (r < 130) {
            const float4* mp = reinterpret_cast<const float4*>(&Mm[r * NPAD]);
            const float4* pa = reinterpret_cast<const float4*>(va);
            const float4* pb = reinterpret_cast<const float4*>(vb);
            const float4* pd = reinterpret_cast<const float4*>(vd);
            float aa = 0.f, ab = 0.f, ad = 0.f;
#pragma unroll
            for (int q = 0; q < 33; ++q) {
                float4 m = mp[q];
                float4 xa = pa[q], xb = pb[q], xd = pd[q];
                aa = fmaf(m.x, xa.x, fmaf(m.y, xa.y, fmaf(m.z, xa.z, fmaf(m.w, xa.w, aa))));
                ab = fmaf(m.x, xb.x, fmaf(m.y, xb.y, fmaf(m.z, xb.z, fmaf(m.w, xb.w, ab))));
                ad = fmaf(m.x, xd.x, fmaf(m.y, xd.y, fmaf(m.z, xd.z, fmaf(m.w, xd.w, ad))));
            }
            na[r] = aa; nb[r] = ab; nd[r] = ad;
        }
        __syncthreads();
        if (r < 130) {
            if (st == 1) { ws[OFF_W + 5 * 130 + r] = nb[r]; ws[OFF_W + 6 * 130 + r] = nd[r] + c1bs[r]; a1s[r] = na[r]; }
            if (st == 2) { ws[OFF_W + 3 * 130 + r] = nb[r]; ws[OFF_W + 4 * 130 + r] = nd[r] + a1s[r]; a2s[r] = na[r]; }
            if (st == 3) { ws[OFF_W + 0 * 130 + r] = na[r]; ws[OFF_W + 1 * 130 + r] = nb[r]; ws[OFF_W + 2 * 130 + r] = nd[r] + a2s[r]; }
            va[r] = na[r]; vb[r] = nb[r]; vd[r] = nd[r];
        }
        __syncthreads();
    }
}

// ---------------- gper: periodic forcing P[m][r], m=0..2879 -------------
__global__ __launch_bounds__(256) void gper_kernel(float* __restrict__ ws) {
    const int tid = threadIdx.x;
    const int n0 = blockIdx.x * 32;
    const float* C1T = ws + OFF_C1T;
    const float* C2T = ws + OFF_C2T;
    const float* C1 = ws + OFF_C1;
    const float* C2 = ws + OFF_C2;
    const float* amp = ws + OFF_AMP;
    const float* cph = ws + OFF_CPH;
    const float* sph = ws + OFF_SPH;
    const float* sh  = ws + OFF_SH;
    float* P = ws + OFF_GP;

    __shared__ __align__(16) float qgT[128][36];
    __shared__ __align__(16) float qmT[128][36];
    __shared__ float sth[65], cth[65];

    for (int j = tid; j < 65; j += 256) {
        float t = (j < 33) ? (float)(n0 + j) * 30.0f
                           : (float)(n0 + j - 33) * 30.0f + 15.0f;
        float a = t * OMEGA;
        sth[j] = sinf(a);
        cth[j] = cosf(a);
    }
    __syncthreads();

    for (int p = tid; p < 65 * 128; p += 256) {
        int j = p >> 7, i = p & 127;
        float s = sth[j] * cph[i] + cth[j] * sph[i];
        float v = amp[i] / (1.0f + __expf(-sh[i] * s));
        if (j < 33) qgT[i][j] = v; else qmT[i][j - 33] = v;
    }
    __syncthreads();

    const int rr = tid & 127;
    const int half = tid >> 7;
    const int r = rr + 2;
    float acc1[16], acc2[16];
#pragma unroll
    for (int w = 0; w < 16; ++w) { acc1[w] = 0.0f; acc2[w] = 0.0f; }

    for (int k = 0; k < 128; ++k) {
        float c1 = C1T[(k << 7) + rr];
        float c2 = C2T[(k << 7) + rr];
        const float4* q1p = reinterpret_cast<const float4*>(&qgT[k][half * 16]);
        const float4* q2p = reinterpret_cast<const float4*>(&qmT[k][half * 16]);
#pragma unroll
        for (int w = 0; w < 4; ++w) {
            float4 a = q1p[w];
            float4 b = q2p[w];
            acc1[4 * w + 0] = fmaf(c1, a.x, acc1[4 * w + 0]);
            acc1[4 * w + 1] = fmaf(c1, a.y, acc1[4 * w + 1]);
            acc1[4 * w + 2] = fmaf(c1, a.z, acc1[4 * w + 2]);
            acc1[4 * w + 3] = fmaf(c1, a.w, acc1[4 * w + 3]);
            acc2[4 * w + 0] = fmaf(c2, b.x, acc2[4 * w + 0]);
            acc2[4 * w + 1] = fmaf(c2, b.y, acc2[4 * w + 1]);
            acc2[4 * w + 2] = fmaf(c2, b.z, acc2[4 * w + 2]);
            acc2[4 * w + 3] = fmaf(c2, b.w, acc2[4 * w + 3]);
        }
    }
#pragma unroll
    for (int w = 0; w < 16; ++w) {
        int n = half * 16 + w;
        P[(n0 + n) * 130 + r] = acc1[w] + acc2[w] + 5.0f * qgT[rr][n + 1];
    }

    if (tid < 64) {
        int r2 = tid >> 5;
        int n = tid & 31;
        float acc = 0.0f;
        for (int k = 0; k < 128; ++k) {
            acc = fmaf(C1[r2 * NPAD + 2 + k], qgT[k][n], acc);
            acc = fmaf(C2[r2 * NPAD + 2 + k], qmT[k][n], acc);
        }
        P[(n0 + n) * 130 + r2] = acc;
    }
}

// ---------------- pdouble: D[m] = Mat*S[m] + S[(m+shift)%PERIOD] -------------
__global__ __launch_bounds__(192) void pdouble_kernel(float* __restrict__ ws,
                                                      int offD, int offS, int offMat, int shift) {
    const int m0 = blockIdx.x * 16;
    const int tid = threadIdx.x;
    const float* S = ws + offS;
    const float* Mat = ws + offMat;
    float* D = ws + offD;
    __shared__ __align__(16) float xs2[16][132];
    for (int p = tid; p < 16 * 132; p += 192) {
        int i = p / 132, rr = p - i * 132;
        xs2[i][rr] = (rr < 130) ? S[(m0 + i) * 130 + rr] : 0.0f;
    }
    __syncthreads();
    const int r = tid;
    if (r < 130) {
        float acc[16];
#pragma unroll
        for (int i = 0; i < 16; ++i) acc[i] = 0.0f;
        const float4* mp = reinterpret_cast<const float4*>(&Mat[r * NPAD]);
        for (int q = 0; q < 33; ++q) {
            float4 m = mp[q];
#pragma unroll
            for (int i = 0; i < 16; ++i) {
                float4 x = reinterpret_cast<const float4*>(xs2[i])[q];
                acc[i] = fmaf(m.x, x.x, fmaf(m.y, x.y, fmaf(m.z, x.z, fmaf(m.w, x.w, acc[i]))));
            }
        }
#pragma unroll
        for (int i = 0; i < 16; ++i) {
            int ms = m0 + i + shift; if (ms >= PERIOD) ms -= PERIOD;
            D[(m0 + i) * 130 + r] = acc[i] + S[ms * 130 + r];
        }
    }
}

// ---------------- ttab ----------------
__global__ __launch_bounds__(256) void ttab_kernel(const float* __restrict__ tout_v,
                                                   float* __restrict__ ws) {
    int n = blockIdx.x * 256 + threadIdx.x;
    if (n < 131080) {
        float t = (float)n * 30.0f;
        float2* TT = reinterpret_cast<float2*>(ws + OFF_TT);
        TT[n] = make_float2(interp_tout(t, tout_v), interp_tout(t + 15.0f, tout_v));
    }
}

// ---------------- chunk_accum: stride-4 scan with M^4 ----
__global__ __launch_bounds__(192, 2) void chunk_accum_kernel(float* __restrict__ ws) {
    const int c = blockIdx.x;
    const int r = threadIdx.x;
    const float* M4 = ws + OFF_M4;
    const float* P4 = ws + OFF_GP4;
    const float2* TT = reinterpret_cast<const float2*>(ws + OFF_TT);

    __shared__ __align__(16) float xs[2][132];
    float4 mr[33];
    float w0 = 0.f, w1 = 0.f, w2 = 0.f, w3 = 0.f, w4 = 0.f, w5 = 0.f, w6 = 0.f, w7 = 0.f, w8 = 0.f;
    if (r < 130) {
#pragma unroll
        for (int q = 0; q < 33; ++q) {
            mr[q] = reinterpret_cast<const float4*>(&M4[r * NPAD])[q];
            PIN4(mr[q]);
        }
        w0 = ws[OFF_W + 0 * 130 + r]; w1 = ws[OFF_W + 1 * 130 + r]; w2 = ws[OFF_W + 2 * 130 + r];
        w3 = ws[OFF_W + 3 * 130 + r]; w4 = ws[OFF_W + 4 * 130 + r]; w5 = ws[OFF_W + 5 * 130 + r];
        w6 = ws[OFF_W + 6 * 130 + r]; w7 = ws[OFF_W + 7 * 130 + r]; w8 = ws[OFF_W + 8 * 130 + r];
    }
    if (r < 132) { xs[0][r] = 0.0f; xs[1][r] = 0.0f; }
    __syncthreads();

    const int base = c * LCH;
    int mu = base % PERIOD;
    float pv = (r < 130) ? P4[mu * 130 + r] : 0.0f;
    int cur = 0;
    for (int u = 0; u < 32; ++u) {
        if (r < 130) {
            const int n = base + 4 * u;
            float2 t0 = TT[n], t1 = TT[n + 1], t2 = TT[n + 2], t3 = TT[n + 3];
            float tg4 = TT[n + 4].x;
            float gcur = pv
                + t0.x * w0 + t0.y * w1 + t1.x * w2 + t1.y * w3
                + t2.x * w4 + t2.y * w5 + t3.x * w6 + t3.y * w7 + tg4 * w8;
            mu = (mu + 4 >= PERIOD) ? mu + 4 - PERIOD : mu + 4;
            if (u + 1 < 32) pv = P4[mu * 130 + r];
            const float4* xp = reinterpret_cast<const float4*>(xs[cur]);
            float a0 = 0.f, a1 = 0.f, a2 = 0.f, a3 = 0.f;
#pragma unroll
            for (int q = 0; q < 33; ++q) {
                float4 xv = xp[q];
                a0 = fmaf(mr[q].x, xv.x, a0);
                a1 = fmaf(mr[q].y, xv.y, a1);
                a2 = fmaf(mr[q].z, xv.z, a2);
                a3 = fmaf(mr[q].w, xv.w, a3);
            }
            float val = (a0 + a1) + (a2 + a3) + gcur;
            xs[cur ^ 1][r] = val;
            if (u == 15) ws[OFF_S64 + c * 130 + r] = val;   // state after 64 steps
        }
        __syncthreads();
        cur ^= 1;
    }
    if (r < 130) ws[OFF_G + c * 130 + r] = xs[cur][r];
}

// ---------------- superaccum: SA_s = sum M128^{15-i} G[16s+i], s=0..62 --------
__global__ __launch_bounds__(192, 2) void superaccum_kernel(float* __restrict__ ws) {
    const int s = blockIdx.x;
    const int r = threadIdx.x;
    const float* MP = ws + OFF_M128;
    const float* G = ws + OFF_G;

    __shared__ __align__(16) float xs[2][132];
    float4 mr[33];
    if (r < 130) {
#pragma unroll
        for (int q = 0; q < 33; ++q) {
            mr[q] = reinterpret_cast<const float4*>(&MP[r * NPAD])[q];
            PIN4(mr[q]);
        }
    }
    if (r < 132) { xs[0][r] = 0.0f; xs[1][r] = 0.0f; }
    __syncthreads();

    int cur = 0;
    for (int i = 0; i < 16; ++i) {
        if (r < 130) {
            const float4* xp = reinterpret_cast<const float4*>(xs[cur]);
            float a0 = 0.f, a1 = 0.f, a2 = 0.f, a3 = 0.f;
#pragma unroll
            for (int q = 0; q < 33; ++q) {
                float4 xv = xp[q];
                a0 = fmaf(mr[q].x, xv.x, a0);
                a1 = fmaf(mr[q].y, xv.y, a1);
                a2 = fmaf(mr[q].z, xv.z, a2);
                a3 = fmaf(mr[q].w, xv.w, a3);
            }
            xs[cur ^ 1][r] = (a0 + a1) + (a2 + a3) + G[(16 * s + i) * 130 + r];
        }
        __syncthreads();
        cur ^= 1;
    }
    if (r < 130) ws[OFF_SA + s * 130 + r] = xs[cur][r];
}

// ---------------- superbound: xb[16(s+1)] = M2K xb[16s] + SA_s, s=0..62 -------
__global__ __launch_bounds__(192, 2) void superbound_kernel(float* __restrict__ ws) {
    const int r = threadIdx.x;
    const float* M2K = ws + OFF_M2K;
    const float* SA = ws + OFF_SA;
    float* xb = ws + OFF_XB;

    __shared__ __align__(16) float xs[2][132];
    float4 mr[33];
    if (r < 130) {
#pragma unroll
        for (int q = 0; q < 33; ++q) {
            mr[q] = reinterpret_cast<const float4*>(&M2K[r * NPAD])[q];
            PIN4(mr[q]);
        }
    }
    if (r < 132) { xs[0][r] = (r < 130) ? xb[r] : 0.0f; xs[1][r] = 0.0f; }
    __syncthreads();

    int cur = 0;
    for (int s = 0; s < 63; ++s) {
        if (r < 130) {
            const float4* xp = reinterpret_cast<const float4*>(xs[cur]);
            float a0 = 0.f, a1 = 0.f, a2 = 0.f, a3 = 0.f;
#pragma unroll
            for (int q = 0; q < 33; ++q) {
                float4 xv = xp[q];
                a0 = fmaf(mr[q].x, xv.x, a0);
                a1 = fmaf(mr[q].y, xv.y, a1);
                a2 = fmaf(mr[q].z, xv.z, a2);
                a3 = fmaf(mr[q].w, xv.w, a3);
            }
            float val = (a0 + a1) + (a2 + a3) + SA[s * 130 + r];
            xs[cur ^ 1][r] = val;
            xb[(16 * s + 16) * 130 + r] = val;
        }
        __syncthreads();
        cur ^= 1;
    }
}

// ---------------- chunkbound: 64 blocks x 15 steps with M128 ----------
__global__ __launch_bounds__(192, 2) void chunkbound_kernel(float* __restrict__ ws) {
    const int s = blockIdx.x;
    const int r = threadIdx.x;
    const float* MP = ws + OFF_M128;
    const float* G = ws + OFF_G;
    float* xb = ws + OFF_XB;

    __shared__ __align__(16) float xs[2][132];
    float4 mr[33];
    if (r < 130) {
#pragma unroll
        for (int q = 0; q < 33; ++q) {
            mr[q] = reinterpret_cast<const float4*>(&MP[r * NPAD])[q];
            PIN4(mr[q]);
        }
    }
    if (r < 132) { xs[0][r] = (r < 130) ? xb[(16 * s) * 130 + r] : 0.0f; xs[1][r] = 0.0f; }
    __syncthreads();

    int cur = 0;
    for (int i = 0; i < 15; ++i) {
        if (r < 130) {
            const float4* xp = reinterpret_cast<const float4*>(xs[cur]);
            float a0 = 0.f, a1 = 0.f, a2 = 0.f, a3 = 0.f;
#pragma unroll
            for (int q = 0; q < 33; ++q) {
                float4 xv = xp[q];
                a0 = fmaf(mr[q].x, xv.x, a0);
                a1 = fmaf(mr[q].y, xv.y, a1);
                a2 = fmaf(mr[q].z, xv.z, a2);
                a3 = fmaf(mr[q].w, xv.w, a3);
            }
            float val = (a0 + a1) + (a2 + a3) + G[(16 * s + i) * 130 + r];
            xs[cur ^ 1][r] = val;
            xb[(16 * s + i + 1) * 130 + r] = val;
        }
        __syncthreads();
        cur ^= 1;
    }
}

// ---------------- subbound: xb2[2c]=xb[c]; xb2[2c+1]=M64 xb[c]+S64[c] -------
__global__ __launch_bounds__(192, 2) void subbound_kernel(float* __restrict__ ws) {
    const int c = blockIdx.x;
    const int r = threadIdx.x;
    const float* M64 = ws + OFF_M64;
    const float* xb = ws + OFF_XB;
    float* xb2 = ws + OFF_XB2;

    __shared__ __align__(16) float xs[132];
    if (r < 132) xs[r] = (r < 130) ? xb[c * 130 + r] : 0.0f;
    __syncthreads();
    if (r < 130) {
        const float4* xp = reinterpret_cast<const float4*>(xs);
        const float4* mp = reinterpret_cast<const float4*>(&M64[r * NPAD]);
        float a0 = 0.f, a1 = 0.f, a2 = 0.f, a3 = 0.f;
#pragma unroll
        for (int q = 0; q < 33; ++q) {
            float4 m = mp[q];
            float4 xv = xp[q];
            a0 = fmaf(m.x, xv.x, a0);
            a1 = fmaf(m.y, xv.y, a1);
            a2 = fmaf(m.z, xv.z, a2);
            a3 = fmaf(m.w, xv.w, a3);
        }
        xb2[(2 * c) * 130 + r] = xs[r];
        xb2[(2 * c + 1) * 130 + r] = (a0 + a1) + (a2 + a3) + ws[OFF_S64 + c * 130 + r];
    }
}

// ---------------- emit: 2048 half-chunks x <=64 steps, g on the fly ---------
__global__ __launch_bounds__(192, 2) void chunk_emit_kernel(float* __restrict__ ws,
                                                            float* __restrict__ out) {
    const int ec = blockIdx.x;
    const int r = threadIdx.x;
    const float* Mm = ws + OFF_M;
    const float* P = ws + OFF_GP;
    const float2* TT = reinterpret_cast<const float2*>(ws + OFF_TT);
    const float* xb2 = ws + OFF_XB2;

    __shared__ __align__(16) float xs[2][132];
    float4 mr[33];
    float c1br = 0.f, c2br = 0.f, c3br = 0.f;
    if (r < 130) {
#pragma unroll
        for (int q = 0; q < 33; ++q) {
            mr[q] = reinterpret_cast<const float4*>(&Mm[r * NPAD])[q];
            PIN4(mr[q]);
        }
        c1br = ws[OFF_C1B + r]; c2br = ws[OFF_C2B + r]; c3br = ws[OFF_C3B + r];
    }
    if (r < 132) { xs[0][r] = (r < 130) ? xb2[ec * 130 + r] : 0.0f; xs[1][r] = 0.0f; }
    __syncthreads();

    const int base = ec * 64;
    const int len = min(64, TSTEPS - base);
    int m = base % PERIOD;
    float pv = (r < 130) ? P[m * 130 + r] : 0.0f;
    float2 tc = TT[base], tn = TT[base + 1];
    int cur = 0;
    for (int j = 0; j < len; ++j) {
        if (r < 130) {
            float gcur = pv + tc.x * c1br + tc.y * c2br + tn.x * c3br;
            m = (m + 1 == PERIOD) ? 0 : m + 1;
            if (j + 1 < len) { pv = P[m * 130 + r]; tc = tn; tn = TT[base + j + 2]; }
            const float4* xp = reinterpret_cast<const float4*>(xs[cur]);
            float a0 = 0.f, a1 = 0.f, a2 = 0.f, a3 = 0.f;
#pragma unroll
            for (int q = 0; q < 33; ++q) {
                float4 xv = xp[q];
                a0 = fmaf(mr[q].x, xv.x, a0);
                a1 = fmaf(mr[q].y, xv.y, a1);
                a2 = fmaf(mr[q].z, xv.z, a2);
                a3 = fmaf(mr[q].w, xv.w, a3);
            }
            float val = (a0 + a1) + (a2 + a3) + gcur;
            xs[cur ^ 1][r] = val;
            if (r >= 2) out[(base + j + 1) * 128 + (r - 2)] = val;
        }
        __syncthreads();
        cur ^= 1;
    }
}

extern "C" void kernel_launch(void* const* d_in, const int* in_sizes, int n_in,
                              void* d_out, int out_size, void* d_ws, size_t ws_size,
                              hipStream_t stream) {
    const float* params  = (const float*)d_in[1];
    const float* heating = (const float*)d_in[2];
    const float* Bm      = (const float*)d_in[3];
    const float* tout_v  = (const float*)d_in[5];
    float* out = (float*)d_out;
    float* ws = (float*)d_ws;

    build_A_kernel<<<1, 256, 0, stream>>>(params, heating, Bm, tout_v, ws, out);

    mm_kernel<<<130, 192, 0, stream>>>(ws, OFF_A2, OFF_A, OFF_A);   // A^2
    mm34_kernel<<<260, 192, 0, stream>>>(ws);                       // A^3, A^4
    combine_kernel<<<67, 256, 0, stream>>>(ws);                     // M,C1,C2,+T
    vecs2_kernel<<<1, 192, 0, stream>>>(Bm, ws);                    // c*b + W0..8
    gper_kernel<<<90, 256, 0, stream>>>(ws);                        // periodic P
    ttab_kernel<<<513, 256, 0, stream>>>(tout_v, ws);               // tout tables

    // squarings: M^2..M^2048 (persist M^2, M^4, M^64, M^128, M^2048)
    mm_kernel<<<130, 192, 0, stream>>>(ws, OFF_M2,   OFF_M,    OFF_M);    // M^2
    mm_kernel<<<130, 192, 0, stream>>>(ws, OFF_M4,   OFF_M2,   OFF_M2);   // M^4
    mm_kernel<<<130, 192, 0, stream>>>(ws, OFF_P1,   OFF_M4,   OFF_M4);   // M^8
    mm_kernel<<<130, 192, 0, stream>>>(ws, OFF_P2,   OFF_P1,   OFF_P1);   // M^16
    mm_kernel<<<130, 192, 0, stream>>>(ws, OFF_P1,   OFF_P2,   OFF_P2);   // M^32
    mm_kernel<<<130, 192, 0, stream>>>(ws, OFF_M64,  OFF_P1,   OFF_P1);   // M^64
    mm_kernel<<<130, 192, 0, stream>>>(ws, OFF_M128, OFF_M64,  OFF_M64);  // M^128
    mm_kernel<<<130, 192, 0, stream>>>(ws, OFF_P1,   OFF_M128, OFF_M128); // M^256
    mm_kernel<<<130, 192, 0, stream>>>(ws, OFF_P2,   OFF_P1,   OFF_P1);   // M^512
    mm_kernel<<<130, 192, 0, stream>>>(ws, OFF_P1,   OFF_P2,   OFF_P2);   // M^1024
    mm_kernel<<<130, 192, 0, stream>>>(ws, OFF_M2K,  OFF_P1,   OFF_P1);   // M^2048

    // periodic-forcing doubling: P2 = M*P[m] + P[m+1]; P4 = M^2*P2[m] + P2[m+2]
    pdouble_kernel<<<180, 192, 0, stream>>>(ws, OFF_GP2, OFF_GP,  OFF_M,  1);
    pdouble_kernel<<<180, 192, 0, stream>>>(ws, OFF_GP4, OFF_GP2, OFF_M2, 2);

    chunk_accum_kernel<<<NCH, 192, 0, stream>>>(ws);
    superaccum_kernel<<<63, 192, 0, stream>>>(ws);
    superbound_kernel<<<1, 192, 0, stream>>>(ws);
    chunkbound_kernel<<<64, 192, 0, stream>>>(ws);
    subbound_kernel<<<NCH, 192, 0, stream>>>(ws);
    chunk_emit_kernel<<<2 * NCH, 192, 0, stream>>>(ws, out);
}

// Round 7
// 505.209 us; speedup vs baseline: 1.1645x; 1.1645x over previous
//
#include <hip/hip_runtime.h>
#include <math.h>

// ---- problem constants ----
#define NPAD 132                 // padded row stride for 130x130 matrices
#define TSTEPS 131071            // number of RK4 steps (T-1)
#define LCH 128                  // chunk length
#define NCH 1024                 // number of chunks
#define PERIOD 2880              // steps per day: forcing q(t) exactly periodic
#define OMEGA 7.2722052166430399e-05f   // 2*pi/86400

// ---- workspace layout (float offsets) ----
#define OFF_A    0
#define OFF_A2   17160
#define OFF_A3   34320
#define OFF_M    51480
#define OFF_C1   68640
#define OFF_C2   85800
#define OFF_P1   102960
#define OFF_P2   120120          // A^4 until squarings reuse it
#define OFF_M2   137280
#define OFF_M4   154440
#define OFF_M64  171600
#define OFF_M128 188760
#define OFF_M2K  205920
#define OFF_C1T  223080          // [128][128]
#define OFF_C2T  239464
#define OFF_C1B  255848
#define OFF_C2B  255978
#define OFF_C3B  256108
#define OFF_AMP  256238
#define OFF_CPH  256366
#define OFF_SPH  256494
#define OFF_SH   256622
#define OFF_W    256750          // [9][130] stride-4 forcing vectors
#define OFF_G    257920          // [NCH][130]
#define OFF_S64  391040          // [NCH][130] partial at 64 steps
#define OFF_XB   524160          // [NCH][130] chunk boundaries
#define OFF_XB2  657280          // [2*NCH][130] half-chunk boundaries
#define OFF_SA   923520          // [63][130] superchunk accums
#define OFF_GP   931710          // [PERIOD][130] periodic forcing P
#define OFF_GP2  1306110         // [PERIOD][130] P2
#define OFF_GP4  1680510         // [PERIOD][130] P4
#define OFF_TT   2054910         // float2[131080] (tg, tm)

typedef float f4 __attribute__((ext_vector_type(4)));

// Load one 130-float matrix row (33 x dwordx4, 528 B incl. pad) via volatile
// inline asm. r5/r6 lesson: plain loads (even with launch_bounds + reg-pin asm)
// get REMATERIALIZED by the compiler inside the step loop -> 68 KB L2 re-read
// per block per step (~47 TB/s demand, L2-bound). Volatile asm outputs cannot
// be rematerialized, so the row truly stays in VGPRs across the loop.
#define MLOAD(Q, S) asm volatile("global_load_dwordx4 %0, %1, off offset:" S \
                                 : "=v"(mr[Q]) : "v"(base))
__device__ __forceinline__ void load_mrow(const float* base, f4* mr) {
    MLOAD(0, "0");    MLOAD(1, "16");   MLOAD(2, "32");   MLOAD(3, "48");
    MLOAD(4, "64");   MLOAD(5, "80");   MLOAD(6, "96");   MLOAD(7, "112");
    MLOAD(8, "128");  MLOAD(9, "144");  MLOAD(10, "160"); MLOAD(11, "176");
    MLOAD(12, "192"); MLOAD(13, "208"); MLOAD(14, "224"); MLOAD(15, "240");
    MLOAD(16, "256"); MLOAD(17, "272"); MLOAD(18, "288"); MLOAD(19, "304");
    MLOAD(20, "320"); MLOAD(21, "336"); MLOAD(22, "352"); MLOAD(23, "368");
    MLOAD(24, "384"); MLOAD(25, "400"); MLOAD(26, "416"); MLOAD(27, "432");
    MLOAD(28, "448"); MLOAD(29, "464"); MLOAD(30, "480"); MLOAD(31, "496");
    MLOAD(32, "512");
    asm volatile("s_waitcnt vmcnt(0)" ::: "memory");
    __builtin_amdgcn_sched_barrier(0);   // rule #18: block hoisting past the wait
}

__device__ __forceinline__ float sigm(float x) { return 1.0f / (1.0f + expf(-x)); }

__device__ __forceinline__ float interp_tout(float t, const float* __restrict__ tv) {
    float u = t * (1.0f / 3600.0f);
    int idx = (int)u;
    if (idx > 1098) idx = 1098;
    float fr = u - (float)idx;
    float v0 = tv[idx];
    return v0 + fr * (tv[idx + 1] - v0);
}

// ---------------- build_A ----------------
__global__ __launch_bounds__(256) void build_A_kernel(
    const float* __restrict__ params, const float* __restrict__ heating,
    const float* __restrict__ Bm, const float* __restrict__ tout_v,
    float* __restrict__ ws, float* __restrict__ out) {
    const int tid = threadIdx.x;
    float* A = ws + OFF_A;

    for (int idx = tid; idx < 130 * 130; idx += 256) {
        int r = idx / 130, c = idx - r * 130;
        A[r * NPAD + c] = sigm(params[idx]) * 1e-5f;
    }
    for (int r = tid; r < 130; r += 256) { A[r * NPAD + 130] = 0.f; A[r * NPAD + 131] = 0.f; }
    __syncthreads();
    for (int r = tid; r < 130; r += 256) {
        float s = 0.0f;
        for (int k = 0; k < 130; ++k) s += A[r * NPAD + k];
        A[r * NPAD + r] = -s;
    }
    for (int i = tid; i < 128; i += 256) {
        float bd = Bm[(2 + i) * 129 + (1 + i)];
        ws[OFF_AMP + i] = sigm(heating[i * 3]) * 500.0f * bd;
        float ph = heating[i * 3 + 1];
        ws[OFF_CPH + i] = cosf(ph);
        ws[OFF_SPH + i] = sinf(ph);
        ws[OFF_SH + i]  = heating[i * 3 + 2];
    }
    float iv = tout_v[0] + 4.0f;
    for (int i = tid; i < 128; i += 256) out[i] = iv;
    for (int r = tid; r < 130; r += 256) ws[OFF_XB + r] = iv;
}

// ---------------- mm: dst = X*Y, one block per output row ----------
__global__ __launch_bounds__(192) void mm_kernel(float* __restrict__ ws,
                                                 int offD, int offX, int offY) {
    const float* X = ws + offX;
    const float* Y = ws + offY;
    float* dst = ws + offD;
    __shared__ float xrow[130];
    const int r = blockIdx.x;
    const int c = threadIdx.x;
    if (c < 130) xrow[c] = X[r * NPAD + c];
    __syncthreads();
    if (c < 130) {
        float acc = 0.0f;
#pragma unroll 10
        for (int k = 0; k < 130; ++k)
            acc = fmaf(xrow[k], Y[k * NPAD + c], acc);
        dst[r * NPAD + c] = acc;
    }
    if (c >= 130 && c < 132) dst[r * NPAD + c] = 0.0f;
}

// ---------------- mm34: A3 = A*A2 (blocks 0..129), A4 = A2*A2 (130..259) -----
__global__ __launch_bounds__(192) void mm34_kernel(float* __restrict__ ws) {
    const int b = blockIdx.x;
    const bool hi = (b >= 130);
    const int r = hi ? b - 130 : b;
    const float* X = ws + (hi ? OFF_A2 : OFF_A);
    const float* Y = ws + OFF_A2;
    float* dst = ws + (hi ? OFF_P2 : OFF_A3);
    __shared__ float xrow[130];
    const int c = threadIdx.x;
    if (c < 130) xrow[c] = X[r * NPAD + c];
    __syncthreads();
    if (c < 130) {
        float acc = 0.0f;
#pragma unroll 10
        for (int k = 0; k < 130; ++k)
            acc = fmaf(xrow[k], Y[k * NPAD + c], acc);
        dst[r * NPAD + c] = acc;
    }
    if (c >= 130 && c < 132) dst[r * NPAD + c] = 0.0f;
}

// ---------------- combine: M, C1, C2 (+ transposed room blocks) --------------
__global__ __launch_bounds__(256) void combine_kernel(float* __restrict__ ws) {
    int idx = blockIdx.x * 256 + threadIdx.x;
    if (idx >= 130 * 130) return;
    int r = idx / 130, c = idx - r * 130;
    int o = r * NPAD + c;
    const float* A  = ws + OFF_A;
    const float* A2 = ws + OFF_A2;
    const float* A3 = ws + OFF_A3;
    const float* A4 = ws + OFF_P2;
    float eye = (r == c) ? 1.0f : 0.0f;
    float a = A[o], a2 = A2[o], a3 = A3[o], a4 = A4[o];
    float c1v = 5.0f * eye + 150.0f * a + 2250.0f * a2 + 33750.0f * a3;
    float c2v = 20.0f * eye + 300.0f * a + 2250.0f * a2;
    ws[OFF_M  + o] = eye + 30.0f * a + 450.0f * a2 + 4500.0f * a3 + 33750.0f * a4;
    ws[OFF_C1 + o] = c1v;
    ws[OFF_C2 + o] = c2v;
    if (r >= 2 && c >= 2) {
        ws[OFF_C1T + (c - 2) * 128 + (r - 2)] = c1v;
        ws[OFF_C2T + (c - 2) * 128 + (r - 2)] = c2v;
    }
    if (c == 0) {
        ws[OFF_M + r * NPAD + 130] = 0.f; ws[OFF_M + r * NPAD + 131] = 0.f;
        ws[OFF_C1 + r * NPAD + 130] = 0.f; ws[OFF_C1 + r * NPAD + 131] = 0.f;
        ws[OFF_C2 + r * NPAD + 130] = 0.f; ws[OFF_C2 + r * NPAD + 131] = 0.f;
    }
}

// ---------------- vecs2: c1b/c2b/c3b + the 9 stride-4 W vectors --------------
// W0=M3c1b W1=M3c2b W2=M3c3b+M2c1b W3=M2c2b W4=M2c3b+Mc1b W5=Mc2b
// W6=Mc3b+c1b W7=c2b W8=c3b
__global__ __launch_bounds__(192) void vecs2_kernel(const float* __restrict__ Bm,
                                                    float* __restrict__ ws) {
    const int r = threadIdx.x;
    const float* C1 = ws + OFF_C1;
    const float* C2 = ws + OFF_C2;
    const float* Mm = ws + OFF_M;
    __shared__ __align__(16) float va[132], vb[132], vd[132];
    __shared__ __align__(16) float na[132], nb[132], nd[132];
    __shared__ float a1s[130], a2s[130], c1bs[130];

    if (r < 132) { va[r] = 0.f; vb[r] = 0.f; vd[r] = 0.f; na[r] = 0.f; nb[r] = 0.f; nd[r] = 0.f; }
    __syncthreads();
    if (r < 130) {
        float s1 = 0.0f, s2 = 0.0f;
        for (int k = 0; k < 130; ++k) {
            float b0 = Bm[k * 129];
            s1 = fmaf(C1[r * NPAD + k], b0, s1);
            s2 = fmaf(C2[r * NPAD + k], b0, s2);
        }
        float c3 = 5.0f * Bm[r * 129];
        ws[OFF_C1B + r] = s1; ws[OFF_C2B + r] = s2; ws[OFF_C3B + r] = c3;
        ws[OFF_W + 7 * 130 + r] = s2;   // W7
        ws[OFF_W + 8 * 130 + r] = c3;   // W8
        va[r] = s1; vb[r] = s2; vd[r] = c3; c1bs[r] = s1;
    }
    __syncthreads();

    for (int st = 1; st <= 3; ++st) {
        if (r < 130) {
            const f4* mp = reinterpret_cast<const f4*>(&Mm[r * NPAD]);
            const f4* pa = reinterpret_cast<const f4*>(va);
            const f4* pb = reinterpret_cast<const f4*>(vb);
            const f4* pd = reinterpret_cast<const f4*>(vd);
            float aa = 0.f, ab = 0.f, ad = 0.f;
#pragma unroll
            for (int q = 0; q < 33; ++q) {
                f4 m = mp[q];
                f4 xa = pa[q], xb = pb[q], xd = pd[q];
                aa = fmaf(m.x, xa.x, fmaf(m.y, xa.y, fmaf(m.z, xa.z, fmaf(m.w, xa.w, aa))));
                ab = fmaf(m.x, xb.x, fmaf(m.y, xb.y, fmaf(m.z, xb.z, fmaf(m.w, xb.w, ab))));
                ad = fmaf(m.x, xd.x, fmaf(m.y, xd.y, fmaf(m.z, xd.z, fmaf(m.w, xd.w, ad))));
            }
            na[r] = aa; nb[r] = ab; nd[r] = ad;
        }
        __syncthreads();
        if (r < 130) {
            if (st == 1) { ws[OFF_W + 5 * 130 + r] = nb[r]; ws[OFF_W + 6 * 130 + r] = nd[r] + c1bs[r]; a1s[r] = na[r]; }
            if (st == 2) { ws[OFF_W + 3 * 130 + r] = nb[r]; ws[OFF_W + 4 * 130 + r] = nd[r] + a1s[r]; a2s[r] = na[r]; }
            if (st == 3) { ws[OFF_W + 0 * 130 + r] = na[r]; ws[OFF_W + 1 * 130 + r] = nb[r]; ws[OFF_W + 2 * 130 + r] = nd[r] + a2s[r]; }
            va[r] = na[r]; vb[r] = nb[r]; vd[r] = nd[r];
        }
        __syncthreads();
    }
}

// ---------------- gper: periodic forcing P[m][r], m=0..2879 -------------
__global__ __launch_bounds__(256) void gper_kernel(float* __restrict__ ws) {
    const int tid = threadIdx.x;
    const int n0 = blockIdx.x * 32;
    const float* C1T = ws + OFF_C1T;
    const float* C2T = ws + OFF_C2T;
    const float* C1 = ws + OFF_C1;
    const float* C2 = ws + OFF_C2;
    const float* amp = ws + OFF_AMP;
    const float* cph = ws + OFF_CPH;
    const float* sph = ws + OFF_SPH;
    const float* sh  = ws + OFF_SH;
    float* P = ws + OFF_GP;

    __shared__ __align__(16) float qgT[128][36];
    __shared__ __align__(16) float qmT[128][36];
    __shared__ float sth[65], cth[65];

    for (int j = tid; j < 65; j += 256) {
        float t = (j < 33) ? (float)(n0 + j) * 30.0f
                           : (float)(n0 + j - 33) * 30.0f + 15.0f;
        float a = t * OMEGA;
        sth[j] = sinf(a);
        cth[j] = cosf(a);
    }
    __syncthreads();

    for (int p = tid; p < 65 * 128; p += 256) {
        int j = p >> 7, i = p & 127;
        float s = sth[j] * cph[i] + cth[j] * sph[i];
        float v = amp[i] / (1.0f + __expf(-sh[i] * s));
        if (j < 33) qgT[i][j] = v; else qmT[i][j - 33] = v;
    }
    __syncthreads();

    const int rr = tid & 127;
    const int half = tid >> 7;
    const int r = rr + 2;
    float acc1[16], acc2[16];
#pragma unroll
    for (int w = 0; w < 16; ++w) { acc1[w] = 0.0f; acc2[w] = 0.0f; }

    for (int k = 0; k < 128; ++k) {
        float c1 = C1T[(k << 7) + rr];
        float c2 = C2T[(k << 7) + rr];
        const float4* q1p = reinterpret_cast<const float4*>(&qgT[k][half * 16]);
        const float4* q2p = reinterpret_cast<const float4*>(&qmT[k][half * 16]);
#pragma unroll
        for (int w = 0; w < 4; ++w) {
            float4 a = q1p[w];
            float4 b = q2p[w];
            acc1[4 * w + 0] = fmaf(c1, a.x, acc1[4 * w + 0]);
            acc1[4 * w + 1] = fmaf(c1, a.y, acc1[4 * w + 1]);
            acc1[4 * w + 2] = fmaf(c1, a.z, acc1[4 * w + 2]);
            acc1[4 * w + 3] = fmaf(c1, a.w, acc1[4 * w + 3]);
            acc2[4 * w + 0] = fmaf(c2, b.x, acc2[4 * w + 0]);
            acc2[4 * w + 1] = fmaf(c2, b.y, acc2[4 * w + 1]);
            acc2[4 * w + 2] = fmaf(c2, b.z, acc2[4 * w + 2]);
            acc2[4 * w + 3] = fmaf(c2, b.w, acc2[4 * w + 3]);
        }
    }
#pragma unroll
    for (int w = 0; w < 16; ++w) {
        int n = half * 16 + w;
        P[(n0 + n) * 130 + r] = acc1[w] + acc2[w] + 5.0f * qgT[rr][n + 1];
    }

    if (tid < 64) {
        int r2 = tid >> 5;
        int n = tid & 31;
        float acc = 0.0f;
        for (int k = 0; k < 128; ++k) {
            acc = fmaf(C1[r2 * NPAD + 2 + k], qgT[k][n], acc);
            acc = fmaf(C2[r2 * NPAD + 2 + k], qmT[k][n], acc);
        }
        P[(n0 + n) * 130 + r2] = acc;
    }
}

// ---------------- pdouble: D[m] = Mat*S[m] + S[(m+shift)%PERIOD] -------------
__global__ __launch_bounds__(192) void pdouble_kernel(float* __restrict__ ws,
                                                      int offD, int offS, int offMat, int shift) {
    const int m0 = blockIdx.x * 16;
    const int tid = threadIdx.x;
    const float* S = ws + offS;
    const float* Mat = ws + offMat;
    float* D = ws + offD;
    __shared__ __align__(16) float xs2[16][132];
    for (int p = tid; p < 16 * 132; p += 192) {
        int i = p / 132, rr = p - i * 132;
        xs2[i][rr] = (rr < 130) ? S[(m0 + i) * 130 + rr] : 0.0f;
    }
    __syncthreads();
    const int r = tid;
    if (r < 130) {
        float acc[16];
#pragma unroll
        for (int i = 0; i < 16; ++i) acc[i] = 0.0f;
        const f4* mp = reinterpret_cast<const f4*>(&Mat[r * NPAD]);
        for (int q = 0; q < 33; ++q) {
            f4 m = mp[q];
#pragma unroll
            for (int i = 0; i < 16; ++i) {
                f4 x = reinterpret_cast<const f4*>(xs2[i])[q];
                acc[i] = fmaf(m.x, x.x, fmaf(m.y, x.y, fmaf(m.z, x.z, fmaf(m.w, x.w, acc[i]))));
            }
        }
#pragma unroll
        for (int i = 0; i < 16; ++i) {
            int ms = m0 + i + shift; if (ms >= PERIOD) ms -= PERIOD;
            D[(m0 + i) * 130 + r] = acc[i] + S[ms * 130 + r];
        }
    }
}

// ---------------- ttab ----------------
__global__ __launch_bounds__(256) void ttab_kernel(const float* __restrict__ tout_v,
                                                   float* __restrict__ ws) {
    int n = blockIdx.x * 256 + threadIdx.x;
    if (n < 131080) {
        float t = (float)n * 30.0f;
        float2* TT = reinterpret_cast<float2*>(ws + OFF_TT);
        TT[n] = make_float2(interp_tout(t, tout_v), interp_tout(t + 15.0f, tout_v));
    }
}

// ---------------- chunk_accum: stride-4 scan with M^4 ----
__global__ __launch_bounds__(192, 2) void chunk_accum_kernel(float* __restrict__ ws) {
    const int c = blockIdx.x;
    const int r = threadIdx.x;
    const float* M4 = ws + OFF_M4;
    const float* P4 = ws + OFF_GP4;
    const float2* TT = reinterpret_cast<const float2*>(ws + OFF_TT);

    __shared__ __align__(16) float xs[2][132];
    f4 mr[33];
    float w0 = 0.f, w1 = 0.f, w2 = 0.f, w3 = 0.f, w4 = 0.f, w5 = 0.f, w6 = 0.f, w7 = 0.f, w8 = 0.f;
    if (r < 130) {
        load_mrow(&M4[r * NPAD], mr);
        w0 = ws[OFF_W + 0 * 130 + r]; w1 = ws[OFF_W + 1 * 130 + r]; w2 = ws[OFF_W + 2 * 130 + r];
        w3 = ws[OFF_W + 3 * 130 + r]; w4 = ws[OFF_W + 4 * 130 + r]; w5 = ws[OFF_W + 5 * 130 + r];
        w6 = ws[OFF_W + 6 * 130 + r]; w7 = ws[OFF_W + 7 * 130 + r]; w8 = ws[OFF_W + 8 * 130 + r];
    }
    if (r < 132) { xs[0][r] = 0.0f; xs[1][r] = 0.0f; }
    __syncthreads();

    const int base = c * LCH;
    int mu = base % PERIOD;
    float pv = (r < 130) ? P4[mu * 130 + r] : 0.0f;
    int cur = 0;
    for (int u = 0; u < 32; ++u) {
        if (r < 130) {
            const int n = base + 4 * u;
            float2 t0 = TT[n], t1 = TT[n + 1], t2 = TT[n + 2], t3 = TT[n + 3];
            float tg4 = TT[n + 4].x;
            float gcur = pv
                + t0.x * w0 + t0.y * w1 + t1.x * w2 + t1.y * w3
                + t2.x * w4 + t2.y * w5 + t3.x * w6 + t3.y * w7 + tg4 * w8;
            mu = (mu + 4 >= PERIOD) ? mu + 4 - PERIOD : mu + 4;
            if (u + 1 < 32) pv = P4[mu * 130 + r];
            const f4* xp = reinterpret_cast<const f4*>(xs[cur]);
            float a0 = 0.f, a1 = 0.f, a2 = 0.f, a3 = 0.f;
#pragma unroll
            for (int q = 0; q < 33; ++q) {
                f4 xv = xp[q];
                a0 = fmaf(mr[q].x, xv.x, a0);
                a1 = fmaf(mr[q].y, xv.y, a1);
                a2 = fmaf(mr[q].z, xv.z, a2);
                a3 = fmaf(mr[q].w, xv.w, a3);
            }
            float val = (a0 + a1) + (a2 + a3) + gcur;
            xs[cur ^ 1][r] = val;
            if (u == 15) ws[OFF_S64 + c * 130 + r] = val;   // state after 64 steps
        }
        __syncthreads();
        cur ^= 1;
    }
    if (r < 130) ws[OFF_G + c * 130 + r] = xs[cur][r];
}

// ---------------- superaccum: SA_s = sum M128^{15-i} G[16s+i], s=0..62 --------
__global__ __launch_bounds__(192, 2) void superaccum_kernel(float* __restrict__ ws) {
    const int s = blockIdx.x;
    const int r = threadIdx.x;
    const float* MP = ws + OFF_M128;
    const float* G = ws + OFF_G;

    __shared__ __align__(16) float xs[2][132];
    f4 mr[33];
    if (r < 130) load_mrow(&MP[r * NPAD], mr);
    if (r < 132) { xs[0][r] = 0.0f; xs[1][r] = 0.0f; }
    __syncthreads();

    int cur = 0;
    for (int i = 0; i < 16; ++i) {
        if (r < 130) {
            const f4* xp = reinterpret_cast<const f4*>(xs[cur]);
            float a0 = 0.f, a1 = 0.f, a2 = 0.f, a3 = 0.f;
#pragma unroll
            for (int q = 0; q < 33; ++q) {
                f4 xv = xp[q];
                a0 = fmaf(mr[q].x, xv.x, a0);
                a1 = fmaf(mr[q].y, xv.y, a1);
                a2 = fmaf(mr[q].z, xv.z, a2);
                a3 = fmaf(mr[q].w, xv.w, a3);
            }
            xs[cur ^ 1][r] = (a0 + a1) + (a2 + a3) + G[(16 * s + i) * 130 + r];
        }
        __syncthreads();
        cur ^= 1;
    }
    if (r < 130) ws[OFF_SA + s * 130 + r] = xs[cur][r];
}

// ---------------- superbound: xb[16(s+1)] = M2K xb[16s] + SA_s, s=0..62 -------
__global__ __launch_bounds__(192, 2) void superbound_kernel(float* __restrict__ ws) {
    const int r = threadIdx.x;
    const float* M2K = ws + OFF_M2K;
    const float* SA = ws + OFF_SA;
    float* xb = ws + OFF_XB;

    __shared__ __align__(16) float xs[2][132];
    f4 mr[33];
    if (r < 130) load_mrow(&M2K[r * NPAD], mr);
    if (r < 132) { xs[0][r] = (r < 130) ? xb[r] : 0.0f; xs[1][r] = 0.0f; }
    __syncthreads();

    int cur = 0;
    for (int s = 0; s < 63; ++s) {
        if (r < 130) {
            const f4* xp = reinterpret_cast<const f4*>(xs[cur]);
            float a0 = 0.f, a1 = 0.f, a2 = 0.f, a3 = 0.f;
#pragma unroll
            for (int q = 0; q < 33; ++q) {
                f4 xv = xp[q];
                a0 = fmaf(mr[q].x, xv.x, a0);
                a1 = fmaf(mr[q].y, xv.y, a1);
                a2 = fmaf(mr[q].z, xv.z, a2);
                a3 = fmaf(mr[q].w, xv.w, a3);
            }
            float val = (a0 + a1) + (a2 + a3) + SA[s * 130 + r];
            xs[cur ^ 1][r] = val;
            xb[(16 * s + 16) * 130 + r] = val;
        }
        __syncthreads();
        cur ^= 1;
    }
}

// ---------------- chunkbound: 64 blocks x 15 steps with M128 ----------
__global__ __launch_bounds__(192, 2) void chunkbound_kernel(float* __restrict__ ws) {
    const int s = blockIdx.x;
    const int r = threadIdx.x;
    const float* MP = ws + OFF_M128;
    const float* G = ws + OFF_G;
    float* xb = ws + OFF_XB;

    __shared__ __align__(16) float xs[2][132];
    f4 mr[33];
    if (r < 130) load_mrow(&MP[r * NPAD], mr);
    if (r < 132) { xs[0][r] = (r < 130) ? xb[(16 * s) * 130 + r] : 0.0f; xs[1][r] = 0.0f; }
    __syncthreads();

    int cur = 0;
    for (int i = 0; i < 15; ++i) {
        if (r < 130) {
            const f4* xp = reinterpret_cast<const f4*>(xs[cur]);
            float a0 = 0.f, a1 = 0.f, a2 = 0.f, a3 = 0.f;
#pragma unroll
            for (int q = 0; q < 33; ++q) {
                f4 xv = xp[q];
                a0 = fmaf(mr[q].x, xv.x, a0);
                a1 = fmaf(mr[q].y, xv.y, a1);
                a2 = fmaf(mr[q].z, xv.z, a2);
                a3 = fmaf(mr[q].w, xv.w, a3);
            }
            float val = (a0 + a1) + (a2 + a3) + G[(16 * s + i) * 130 + r];
            xs[cur ^ 1][r] = val;
            xb[(16 * s + i + 1) * 130 + r] = val;
        }
        __syncthreads();
        cur ^= 1;
    }
}

// ---------------- subbound: xb2[2c]=xb[c]; xb2[2c+1]=M64 xb[c]+S64[c] -------
__global__ __launch_bounds__(192, 2) void subbound_kernel(float* __restrict__ ws) {
    const int c = blockIdx.x;
    const int r = threadIdx.x;
    const float* M64 = ws + OFF_M64;
    const float* xb = ws + OFF_XB;
    float* xb2 = ws + OFF_XB2;

    __shared__ __align__(16) float xs[132];
    if (r < 132) xs[r] = (r < 130) ? xb[c * 130 + r] : 0.0f;
    __syncthreads();
    if (r < 130) {
        const f4* xp = reinterpret_cast<const f4*>(xs);
        const f4* mp = reinterpret_cast<const f4*>(&M64[r * NPAD]);
        float a0 = 0.f, a1 = 0.f, a2 = 0.f, a3 = 0.f;
#pragma unroll
        for (int q = 0; q < 33; ++q) {
            f4 m = mp[q];
            f4 xv = xp[q];
            a0 = fmaf(m.x, xv.x, a0);
            a1 = fmaf(m.y, xv.y, a1);
            a2 = fmaf(m.z, xv.z, a2);
            a3 = fmaf(m.w, xv.w, a3);
        }
        xb2[(2 * c) * 130 + r] = xs[r];
        xb2[(2 * c + 1) * 130 + r] = (a0 + a1) + (a2 + a3) + ws[OFF_S64 + c * 130 + r];
    }
}

// ---------------- emit: 2048 half-chunks x <=64 steps, g on the fly ---------
__global__ __launch_bounds__(192, 2) void chunk_emit_kernel(float* __restrict__ ws,
                                                            float* __restrict__ out) {
    const int ec = blockIdx.x;
    const int r = threadIdx.x;
    const float* Mm = ws + OFF_M;
    const float* P = ws + OFF_GP;
    const float2* TT = reinterpret_cast<const float2*>(ws + OFF_TT);
    const float* xb2 = ws + OFF_XB2;

    __shared__ __align__(16) float xs[2][132];
    f4 mr[33];
    float c1br = 0.f, c2br = 0.f, c3br = 0.f;
    if (r < 130) {
        load_mrow(&Mm[r * NPAD], mr);
        c1br = ws[OFF_C1B + r]; c2br = ws[OFF_C2B + r]; c3br = ws[OFF_C3B + r];
    }
    if (r < 132) { xs[0][r] = (r < 130) ? xb2[ec * 130 + r] : 0.0f; xs[1][r] = 0.0f; }
    __syncthreads();

    const int base = ec * 64;
    const int len = min(64, TSTEPS - base);
    int m = base % PERIOD;
    float pv = (r < 130) ? P[m * 130 + r] : 0.0f;
    float2 tc = TT[base], tn = TT[base + 1];
    int cur = 0;
    for (int j = 0; j < len; ++j) {
        if (r < 130) {
            float gcur = pv + tc.x * c1br + tc.y * c2br + tn.x * c3br;
            m = (m + 1 == PERIOD) ? 0 : m + 1;
            if (j + 1 < len) { pv = P[m * 130 + r]; tc = tn; tn = TT[base + j + 2]; }
            const f4* xp = reinterpret_cast<const f4*>(xs[cur]);
            float a0 = 0.f, a1 = 0.f, a2 = 0.f, a3 = 0.f;
#pragma unroll
            for (int q = 0; q < 33; ++q) {
                f4 xv = xp[q];
                a0 = fmaf(mr[q].x, xv.x, a0);
                a1 = fmaf(mr[q].y, xv.y, a1);
                a2 = fmaf(mr[q].z, xv.z, a2);
                a3 = fmaf(mr[q].w, xv.w, a3);
            }
            float val = (a0 + a1) + (a2 + a3) + gcur;
            xs[cur ^ 1][r] = val;
            if (r >= 2) out[(base + j + 1) * 128 + (r - 2)] = val;
        }
        __syncthreads();
        cur ^= 1;
    }
}

extern "C" void kernel_launch(void* const* d_in, const int* in_sizes, int n_in,
                              void* d_out, int out_size, void* d_ws, size_t ws_size,
                              hipStream_t stream) {
    const float* params  = (const float*)d_in[1];
    const float* heating = (const float*)d_in[2];
    const float* Bm      = (const float*)d_in[3];
    const float* tout_v  = (const float*)d_in[5];
    float* out = (float*)d_out;
    float* ws = (float*)d_ws;

    build_A_kernel<<<1, 256, 0, stream>>>(params, heating, Bm, tout_v, ws, out);

    mm_kernel<<<130, 192, 0, stream>>>(ws, OFF_A2, OFF_A, OFF_A);   // A^2
    mm34_kernel<<<260, 192, 0, stream>>>(ws);                       // A^3, A^4
    combine_kernel<<<67, 256, 0, stream>>>(ws);                     // M,C1,C2,+T
    vecs2_kernel<<<1, 192, 0, stream>>>(Bm, ws);                    // c*b + W0..8
    gper_kernel<<<90, 256, 0, stream>>>(ws);                        // periodic P
    ttab_kernel<<<513, 256, 0, stream>>>(tout_v, ws);               // tout tables

    // squarings: M^2..M^2048 (persist M^2, M^4, M^64, M^128, M^2048)
    mm_kernel<<<130, 192, 0, stream>>>(ws, OFF_M2,   OFF_M,    OFF_M);    // M^2
    mm_kernel<<<130, 192, 0, stream>>>(ws, OFF_M4,   OFF_M2,   OFF_M2);   // M^4
    mm_kernel<<<130, 192, 0, stream>>>(ws, OFF_P1,   OFF_M4,   OFF_M4);   // M^8
    mm_kernel<<<130, 192, 0, stream>>>(ws, OFF_P2,   OFF_P1,   OFF_P1);   // M^16
    mm_kernel<<<130, 192, 0, stream>>>(ws, OFF_P1,   OFF_P2,   OFF_P2);   // M^32
    mm_kernel<<<130, 192, 0, stream>>>(ws, OFF_M64,  OFF_P1,   OFF_P1);   // M^64
    mm_kernel<<<130, 192, 0, stream>>>(ws, OFF_M128, OFF_M64,  OFF_M64);  // M^128
    mm_kernel<<<130, 192, 0, stream>>>(ws, OFF_P1,   OFF_M128, OFF_M128); // M^256
    mm_kernel<<<130, 192, 0, stream>>>(ws, OFF_P2,   OFF_P1,   OFF_P1);   // M^512
    mm_kernel<<<130, 192, 0, stream>>>(ws, OFF_P1,   OFF_P2,   OFF_P2);   // M^1024
    mm_kernel<<<130, 192, 0, stream>>>(ws, OFF_M2K,  OFF_P1,   OFF_P1);   // M^2048

    // periodic-forcing doubling: P2 = M*P[m] + P[m+1]; P4 = M^2*P2[m] + P2[m+2]
    pdouble_kernel<<<180, 192, 0, stream>>>(ws, OFF_GP2, OFF_GP,  OFF_M,  1);
    pdouble_kernel<<<180, 192, 0, stream>>>(ws, OFF_GP4, OFF_GP2, OFF_M2, 2);

    chunk_accum_kernel<<<NCH, 192, 0, stream>>>(ws);
    superaccum_kernel<<<63, 192, 0, stream>>>(ws);
    superbound_kernel<<<1, 192, 0, stream>>>(ws);
    chunkbound_kernel<<<64, 192, 0, stream>>>(ws);
    subbound_kernel<<<NCH, 192, 0, stream>>>(ws);
    chunk_emit_kernel<<<2 * NCH, 192, 0, stream>>>(ws, out);
}